// Round 9
// baseline (255.393 us; speedup 1.0000x reference)
//
#include <hip/hip_runtime.h>

// APMLSparse: B=4, N=M=4096, D=3.
// loss = sum_rows sum_{kept j} p_ij * d_ij, p = softmax_j(-d_i),
// kept = descending-p prefix until cumulative mass >= P_MIN = 0.8.
//
// R16: INSTRUCTION-CACHE experiment. R15's discriminator: occupancy 46->75%
// yet dur 127->141 => stall is a shared per-CU resource, insensitive to
// residency/ILP/VMEM. Unexplained per-wave span ~60K cyc matches I-fetch
// misses over ~26KB of straight-line fully-unrolled code (> I$, zero
// reuse, 12-24 waves thrashing). Session-wide, duration tracked STATIC
// CODE SIZE (R8/R11 bigger => slower at same VALU count), never occupancy.
// Fix under test: p[64] moves regs -> LDS ([k][lane], conflict-free,
// wave-private); all 64-iter loops ROLLED (unroll 2-4); 1 wave/block.
// Code ~7KB => fits I$. Algorithm phase-identical to R10 (zl order, A0
// dual pass, 4-chain probe association, B/C1/C2/D, tie rule).
// Pre-registered: I$-theory => 60-95us at only ~28% occupancy;
// theory wrong => >=150us and the 125us plateau is declared structural.

#define MCOLS 4096
#define KPT   64            // 4096 / 64 lanes
#define P_MIN 0.8f

// ---- DPP wave64 reductions (old=0 => disabled/out-of-range lanes add 0) ----
template <int CTRL, int RM, int BM, bool BC>
__device__ __forceinline__ float dpp_mov0(float x) {
    return __int_as_float(__builtin_amdgcn_update_dpp(
        0, __float_as_int(x), CTRL, RM, BM, BC));
}
__device__ __forceinline__ float dppSum(float v) {
    v += dpp_mov0<0x111, 0xF, 0xF, true >(v);   // row_shr:1
    v += dpp_mov0<0x112, 0xF, 0xF, true >(v);   // row_shr:2
    v += dpp_mov0<0x114, 0xF, 0xF, true >(v);   // row_shr:4
    v += dpp_mov0<0x118, 0xF, 0xF, true >(v);   // row_shr:8
    v += dpp_mov0<0x142, 0xA, 0xF, false>(v);   // row_bcast15 -> rows 1,3
    v += dpp_mov0<0x143, 0xC, 0xF, false>(v);   // row_bcast31 -> rows 2,3
    return __int_as_float(__builtin_amdgcn_readlane(__float_as_int(v), 63));
}
__device__ __forceinline__ void dppSum2(float& a, float& b) {
    a += dpp_mov0<0x111, 0xF, 0xF, true >(a); b += dpp_mov0<0x111, 0xF, 0xF, true >(b);
    a += dpp_mov0<0x112, 0xF, 0xF, true >(a); b += dpp_mov0<0x112, 0xF, 0xF, true >(b);
    a += dpp_mov0<0x114, 0xF, 0xF, true >(a); b += dpp_mov0<0x114, 0xF, 0xF, true >(b);
    a += dpp_mov0<0x118, 0xF, 0xF, true >(a); b += dpp_mov0<0x118, 0xF, 0xF, true >(b);
    a += dpp_mov0<0x142, 0xA, 0xF, false>(a); b += dpp_mov0<0x142, 0xA, 0xF, false>(b);
    a += dpp_mov0<0x143, 0xC, 0xF, false>(a); b += dpp_mov0<0x143, 0xC, 0xF, false>(b);
    a = __int_as_float(__builtin_amdgcn_readlane(__float_as_int(a), 63));
    b = __int_as_float(__builtin_amdgcn_readlane(__float_as_int(b), 63));
}
__device__ __forceinline__ float dppMax(float v) {   // nonneg inputs only
    v = fmaxf(v, dpp_mov0<0x111, 0xF, 0xF, true >(v));
    v = fmaxf(v, dpp_mov0<0x112, 0xF, 0xF, true >(v));
    v = fmaxf(v, dpp_mov0<0x114, 0xF, 0xF, true >(v));
    v = fmaxf(v, dpp_mov0<0x118, 0xF, 0xF, true >(v));
    v = fmaxf(v, dpp_mov0<0x142, 0xA, 0xF, false>(v));
    v = fmaxf(v, dpp_mov0<0x143, 0xC, 0xF, false>(v));
    return __int_as_float(__builtin_amdgcn_readlane(__float_as_int(v), 63));
}

__global__ __launch_bounds__(64) void apml_row_lds(
        const float* __restrict__ x, const float* __restrict__ y,
        float* __restrict__ partial, float* __restrict__ out) {
    __shared__ __align__(16) float pl[KPT * 64];   // [k][lane]: pl[k*64+lane]
    __shared__ __align__(16) float scomp[256];

    const int lane = threadIdx.x;       // one wave per block
    const int row  = blockIdx.x;
    const int b    = row >> 12;         // row / 4096

    const float x0 = x[row * 3 + 0];
    const float x1 = x[row * 3 + 1];
    const float x2 = x[row * 3 + 2];
    const float* yb = y + (size_t)b * MCOLS * 3;

    // ---- setup (ROLLED): p = exp(-d) -> LDS; Z (serial order) + pmax ----
    float zl = 0.0f, pml = 0.0f;
    #pragma unroll 4
    for (int k = 0; k < KPT; ++k) {
        const int j = k * 64 + lane;
        const float y0 = yb[j * 3 + 0];
        const float y1 = yb[j * 3 + 1];
        const float y2 = yb[j * 3 + 2];
        const float dx = x0 - y0, dy = x1 - y1, dz = x2 - y2;
        const float sq = fmaxf(dx * dx + dy * dy + dz * dz, 1e-12f); // EPS^2
        const float pk = __expf(-sqrtf(sq));
        pl[j] = pk;
        zl  += pk;
        pml  = fmaxf(pml, pk);
    }
    __builtin_amdgcn_s_waitcnt(0);             // drain ds_writes (same wave)
    const float Z    = dppSum(zl);
    const float pmax = dppMax(pml);
    const float target = P_MIN * Z;
    const float pTop = __uint_as_float(__float_as_uint(pmax) + 1u);

    // ---- sampled warm-start: 5 probes on first 256 elements (regs) ----
    const float q0 = pl[lane], q1 = pl[64 + lane];
    const float q2 = pl[128 + lane], q3 = pl[192 + lane];
    float ssl = 0.0f, ssh = pTop;
    {
        float eGl = 16.0f * dppSum(q0 + q1 + q2 + q3);  // Ghat(0)
        float eGh = 0.0f;
        for (int it = 0; it < 5; ++it) {
            float s;
            if (it & 1) {
                s = 0.5f * (ssl + ssh);
            } else {
                const float den = fmaxf(eGl - eGh, 1e-30f);
                s = ssl + (ssh - ssl) * ((eGl - target) / den);
            }
            if (!(s > ssl && s < ssh)) s = 0.5f * (ssl + ssh);
            if (!(s > ssl && s < ssh)) break;
            float m = (q0 >= s) ? q0 : 0.0f;
            m += (q1 >= s) ? q1 : 0.0f;
            m += (q2 >= s) ? q2 : 0.0f;
            m += (q3 >= s) ? q3 : 0.0f;
            m = 16.0f * dppSum(m);
            if (m >= target) { ssl = s; eGl = m; }
            else             { ssh = s; eGh = m; }
        }
    }

    // ---- Phase A0 (ROLLED): dual-threshold pass at (ssl, ssh) ----
    float sl = 0.0f, sh = pTop;
    float Gl = Z,    Gh = 0.0f;
    int   Cl = MCOLS, Ch = 0;
    {
        float ml = 0.0f, mh = 0.0f;
        int   cl_ = 0,   ch_ = 0;
        #pragma unroll 4
        for (int k = 0; k < KPT; ++k) {
            const float pk = pl[k * 64 + lane];
            const bool gl = (pk >= ssl);
            const bool gh = (pk >= ssh);
            ml += gl ? pk : 0.0f; cl_ += (int)__popcll(__ballot(gl));
            mh += gh ? pk : 0.0f; ch_ += (int)__popcll(__ballot(gh));
        }
        dppSum2(ml, mh);
        if (ml >= target) { sl = ssl; Gl = ml; Cl = cl_; }
        else              { sh = ssl; Gh = ml; Ch = cl_; }
        if (mh >= target) { sl = ssh; Gl = mh; Cl = ch_; }
        else if (ssh < sh){ sh = ssh; Gh = mh; Ch = ch_; }
    }

    // ---- Phase A (ROLLED, 4-chain): exact probes until band <= 256 ----
    for (int it = 0; it < 10 && (Cl - Ch) > 256; ++it) {
        float s;
        if (it & 1) {
            s = 0.5f * (sl + sh);
        } else {
            const float den = fmaxf(Gl - Gh, 1e-30f);
            s = sl + (sh - sl) * ((Gl - target) / den);
        }
        if (!(s > sl && s < sh)) s = 0.5f * (sl + sh);
        if (!(s > sl && s < sh)) break;        // ulp-width bracket

        float m0 = 0.0f, m1 = 0.0f, m2 = 0.0f, m3 = 0.0f;
        int   c = 0;
        for (int k = 0; k < KPT; k += 4) {     // rolled; 4 chains inside
            const float p0 = pl[(k    ) * 64 + lane];
            const float p1 = pl[(k + 1) * 64 + lane];
            const float p2 = pl[(k + 2) * 64 + lane];
            const float p3 = pl[(k + 3) * 64 + lane];
            const bool g0 = (p0 >= s), g1 = (p1 >= s);
            const bool g2 = (p2 >= s), g3 = (p3 >= s);
            m0 += g0 ? p0 : 0.0f; c += (int)__popcll(__ballot(g0));
            m1 += g1 ? p1 : 0.0f; c += (int)__popcll(__ballot(g1));
            m2 += g2 ? p2 : 0.0f; c += (int)__popcll(__ballot(g2));
            m3 += g3 ? p3 : 0.0f; c += (int)__popcll(__ballot(g3));
        }
        const float m = dppSum((m0 + m1) + (m2 + m3));
        if (m >= target) { sl = s; Gl = m; Cl = c; }
        else             { sh = s; Gh = m; Ch = c; }
    }

    // ---- Phase B (ROLLED): compact band [sl, sh) to scomp ----
    int C = 0;
    #pragma unroll 2
    for (int k = 0; k < KPT; ++k) {
        const float pk = pl[k * 64 + lane];
        const bool band = (pk >= sl) && (pk < sh);
        const unsigned long long mk = __ballot(band);
        if (band) {
            const unsigned mlo = (unsigned)mk, mhi = (unsigned)(mk >> 32);
            const int within = __builtin_amdgcn_mbcnt_hi(
                                   mhi, __builtin_amdgcn_mbcnt_lo(mlo, 0));
            const int pos = C + within;
            if (pos < 256) scomp[pos] = pk;
        }
        C += (int)__popcll(mk);
    }
    __builtin_amdgcn_s_waitcnt(0);             // drain ds_writes (same wave)
    float cp[4];
    bool  cv[4];
    #pragma unroll
    for (int q = 0; q < 4; ++q) {
        const int idx = q * 64 + lane;
        cv[q] = (idx < C) && (idx < 256);
        cp[q] = cv[q] ? scomp[idx] : 0.0f;
    }

    float pstar, mb = 0.0f;
    int   cnt = 1;
    bool  haveTie;

    if (C > 256) {
        // fallback (rare): keep everything >= sl (off by <=2 boundary elems)
        pstar = (sl > 0.0f) ? __uint_as_float(__float_as_uint(sl) - 1u) : 0.0f;
        haveTie = false;
    } else {
        // ---- Phase C1: cheap fine probes on the compact set (regs) ----
        float lo_s = sl, hi_s = sh, lo_G = Gl, hi_G = Gh;
        int   lo_C = Cl, hi_C = Ch;
        for (int it = 0; it < 10 && (lo_C - hi_C) > 2; ++it) {
            float s;
            if (it & 1) {
                s = 0.5f * (lo_s + hi_s);
            } else {
                const float den = fmaxf(lo_G - hi_G, 1e-30f);
                s = lo_s + (hi_s - lo_s) * ((lo_G - target) / den);
            }
            if (!(s > lo_s && s < hi_s)) s = 0.5f * (lo_s + hi_s);
            if (!(s > lo_s && s < hi_s)) break;

            float m = 0.0f;
            int   c = Ch;
            #pragma unroll
            for (int q = 0; q < 4; ++q) {
                const bool ge = cv[q] && (cp[q] >= s);
                m += ge ? cp[q] : 0.0f;
                c += (int)__popcll(__ballot(ge));
            }
            m = Gh + dppSum(m);
            if (m >= target) { lo_s = s; lo_G = m; lo_C = c; }
            else             { hi_s = s; hi_G = m; hi_C = c; }
        }

        // ---- Phase C2: exact distinct-value walk downward from hi_s ----
        float scur = hi_s, M = hi_G;
        bool ok = false;
        pstar = lo_s;
        for (int e = 0; e < 16; ++e) {
            float vl = 0.0f;
            #pragma unroll
            for (int q = 0; q < 4; ++q)
                vl = fmaxf(vl, (cv[q] && cp[q] < scur) ? cp[q] : 0.0f);
            const float v = dppMax(vl);
            if (!(v > 0.0f)) break;            // fp knife-edge; fallback
            int cvn = 0;
            #pragma unroll
            for (int q = 0; q < 4; ++q)
                cvn += (int)__popcll(__ballot(cv[q] && (cp[q] == v)));
            const float Mn = M + v * (float)cvn;  // exact: ties bit-identical
            if (Mn >= target) { pstar = v; mb = M; cnt = cvn; ok = true; break; }
            M = Mn; scur = v;
        }
        haveTie = ok;
        if (!ok) {
            pstar = (lo_s > 0.0f) ? __uint_as_float(__float_as_uint(lo_s) - 1u)
                                  : 0.0f;
        }
    }

    // ---- Phase D (ROLLED, 4-chain): spd = sum_{p > p*} p * (-log p) ----
    // Per-element term identical (select-to-1); 4-chain association as R14.
    float s0 = 0.0f, s1 = 0.0f, s2 = 0.0f, s3 = 0.0f;
    for (int k = 0; k < KPT; k += 4) {
        const float p0 = pl[(k    ) * 64 + lane];
        const float p1 = pl[(k + 1) * 64 + lane];
        const float p2 = pl[(k + 2) * 64 + lane];
        const float p3 = pl[(k + 3) * 64 + lane];
        const float t0 = (p0 > pstar) ? p0 : 1.0f;   // log(1) = 0
        const float t1 = (p1 > pstar) ? p1 : 1.0f;
        const float t2 = (p2 > pstar) ? p2 : 1.0f;
        const float t3 = (p3 > pstar) ? p3 : 1.0f;
        s0 += t0 * (-__logf(t0));
        s1 += t1 * (-__logf(t1));
        s2 += t2 * (-__logf(t2));
        s3 += t3 * (-__logf(t3));
    }
    const float spd = dppSum((s0 + s1) + (s2 + s3));

    if (lane == 0) {
        float tie = 0.0f;
        if (haveTie) {
            const float R = (target - mb) / pstar;      // exclusive-csum rule
            int q = (int)ceilf(R);
            if (q < 1) q = 1;
            if (q > cnt) q = cnt;
            tie = (float)q * pstar * (-__logf(pstar));
        }
        const float v = (spd + tie) / Z;
        if (partial) partial[row] = v;       // per-row, no atomic
        else         atomicAdd(out, v);      // ws_size fallback
    }
}

// Deterministic 2nd-stage reduce: n (<=16384) floats -> out[0].
__global__ __launch_bounds__(1024) void apml_reduce(
        const float* __restrict__ partial, float* __restrict__ out, int n) {
    __shared__ float s[16];
    const int t = threadIdx.x;
    float a = 0.0f;
    #pragma unroll
    for (int q = 0; q < 16; ++q) {
        const int i = t * 16 + q;
        a += (i < n) ? partial[i] : 0.0f;
    }
    a = dppSum(a);
    if ((t & 63) == 0) s[t >> 6] = a;
    __syncthreads();
    if (t == 0) {
        float r = 0.0f;
        #pragma unroll
        for (int w = 0; w < 16; ++w) r += s[w];
        out[0] = r;
    }
}

extern "C" void kernel_launch(void* const* d_in, const int* in_sizes, int n_in,
                              void* d_out, int out_size, void* d_ws, size_t ws_size,
                              hipStream_t stream) {
    const float* x = (const float*)d_in[0];   // [B, N, 3]
    const float* y = (const float*)d_in[1];   // [B, M, 3]
    float* out = (float*)d_out;               // scalar

    const int nrows = in_sizes[0] / 3;        // B * N = 16384
    const size_t part_bytes = (size_t)nrows * sizeof(float);

    if (d_ws && ws_size >= part_bytes && nrows <= 16384) {
        float* partial = (float*)d_ws;
        apml_row_lds<<<nrows, 64, 0, stream>>>(x, y, partial, out);
        apml_reduce<<<1, 1024, 0, stream>>>(partial, out, nrows);
    } else {
        hipMemsetAsync(out, 0, sizeof(float), stream);   // capture-legal
        apml_row_lds<<<nrows, 64, 0, stream>>>(x, y, nullptr, out);
    }
}

// Round 10
// 180.303 us; speedup vs baseline: 1.4165x; 1.4165x over previous
//
#include <hip/hip_runtime.h>

// APMLSparse: B=4, N=M=4096, D=3.
// loss = sum_rows sum_{kept j} p_ij * d_ij, p = softmax_j(-d_i),
// kept = descending-p prefix until cumulative mass >= P_MIN = 0.8.
//
// R17: R14 base + pd-array Phase D.
// Model validated over 10 rounds: dur = total issue-slots / FIXED ~27-30%
// machine rate. R16's decisive datapoint: VALUBusy*dur identical at 23%
// occupancy (R16) vs 46% (R10) vs 75% (R15) => occupancy/ILP/residency
// irrelevant; only issue-slot count moves duration. Registers are FREE.
// Cut: Phase D recomputed -log(p) ~= d (64 quarter-rate v_log ~ 256 slots
// + 2 VALU/elem). d is live in setup => store pd[k] = p[k]*d (+64 fma,
// +64 regs), Phase D becomes a masked 4-chain add of pd. ~8% issue cut.
// Also MORE faithful to the reference (sums w*d with true d).
// Tie term unchanged (q*p**(-log p*)). All else byte-identical to R14.
// Pre-registered: dispatch 116-121 else declare plateau structural.

#define MCOLS 4096
#define KPT   64            // 4096 / 64 lanes
#define WPB   4             // waves per block
#define P_MIN 0.8f

// ---- DPP wave64 reductions (old=0 => disabled/out-of-range lanes add 0) ----
template <int CTRL, int RM, int BM, bool BC>
__device__ __forceinline__ float dpp_mov0(float x) {
    return __int_as_float(__builtin_amdgcn_update_dpp(
        0, __float_as_int(x), CTRL, RM, BM, BC));
}
__device__ __forceinline__ float dppSum(float v) {
    v += dpp_mov0<0x111, 0xF, 0xF, true >(v);   // row_shr:1
    v += dpp_mov0<0x112, 0xF, 0xF, true >(v);   // row_shr:2
    v += dpp_mov0<0x114, 0xF, 0xF, true >(v);   // row_shr:4
    v += dpp_mov0<0x118, 0xF, 0xF, true >(v);   // row_shr:8
    v += dpp_mov0<0x142, 0xA, 0xF, false>(v);   // row_bcast15 -> rows 1,3
    v += dpp_mov0<0x143, 0xC, 0xF, false>(v);   // row_bcast31 -> rows 2,3
    return __int_as_float(__builtin_amdgcn_readlane(__float_as_int(v), 63));
}
__device__ __forceinline__ void dppSum2(float& a, float& b) {
    a += dpp_mov0<0x111, 0xF, 0xF, true >(a); b += dpp_mov0<0x111, 0xF, 0xF, true >(b);
    a += dpp_mov0<0x112, 0xF, 0xF, true >(a); b += dpp_mov0<0x112, 0xF, 0xF, true >(b);
    a += dpp_mov0<0x114, 0xF, 0xF, true >(a); b += dpp_mov0<0x114, 0xF, 0xF, true >(b);
    a += dpp_mov0<0x118, 0xF, 0xF, true >(a); b += dpp_mov0<0x118, 0xF, 0xF, true >(b);
    a += dpp_mov0<0x142, 0xA, 0xF, false>(a); b += dpp_mov0<0x142, 0xA, 0xF, false>(b);
    a += dpp_mov0<0x143, 0xC, 0xF, false>(a); b += dpp_mov0<0x143, 0xC, 0xF, false>(b);
    a = __int_as_float(__builtin_amdgcn_readlane(__float_as_int(a), 63));
    b = __int_as_float(__builtin_amdgcn_readlane(__float_as_int(b), 63));
}
__device__ __forceinline__ float dppMax(float v) {   // nonneg inputs only
    v = fmaxf(v, dpp_mov0<0x111, 0xF, 0xF, true >(v));
    v = fmaxf(v, dpp_mov0<0x112, 0xF, 0xF, true >(v));
    v = fmaxf(v, dpp_mov0<0x114, 0xF, 0xF, true >(v));
    v = fmaxf(v, dpp_mov0<0x118, 0xF, 0xF, true >(v));
    v = fmaxf(v, dpp_mov0<0x142, 0xA, 0xF, false>(v));
    v = fmaxf(v, dpp_mov0<0x143, 0xC, 0xF, false>(v));
    return __int_as_float(__builtin_amdgcn_readlane(__float_as_int(v), 63));
}

__global__ __launch_bounds__(WPB * 64) void apml_row_wave(
        const float* __restrict__ x, const float* __restrict__ y,
        float* __restrict__ partial, float* __restrict__ out) {
    __shared__ __align__(16) float scomp[WPB * 256];
    __shared__ float wacc[WPB];

    const int tid  = threadIdx.x;
    const int wid  = tid >> 6;
    const int lane = tid & 63;
    const int row  = blockIdx.x * WPB + wid;
    const int b    = row >> 12;                 // row / 4096

    const float x0 = x[row * 3 + 0];
    const float x1 = x[row * 3 + 1];
    const float x2 = x[row * 3 + 2];
    const float* yb = y + (size_t)b * MCOLS * 3;

    // ---- setup: p = exp(-d), pd = p*d, register-resident; Z+pmax DPP ----
    // zl chain order is value-critical (Z) -> serial, unchanged.
    float p[KPT], pd[KPT];
    float zl = 0.0f;
    float pm0 = 0.0f, pm1 = 0.0f, pm2 = 0.0f, pm3 = 0.0f;
    #pragma unroll
    for (int k = 0; k < KPT; ++k) {
        const int j = k * 64 + lane;
        const float y0 = yb[j * 3 + 0];
        const float y1 = yb[j * 3 + 1];
        const float y2 = yb[j * 3 + 2];
        const float dx = x0 - y0, dy = x1 - y1, dz = x2 - y2;
        const float sq = fmaxf(dx * dx + dy * dy + dz * dz, 1e-12f); // EPS^2
        const float dd = sqrtf(sq);
        const float pk = __expf(-dd);
        p[k]  = pk;
        pd[k] = pk * dd;                 // true p*d (reference's own form)
        zl  += pk;
        if      ((k & 3) == 0) pm0 = fmaxf(pm0, pk);
        else if ((k & 3) == 1) pm1 = fmaxf(pm1, pk);
        else if ((k & 3) == 2) pm2 = fmaxf(pm2, pk);
        else                   pm3 = fmaxf(pm3, pk);
    }
    const float Z    = dppSum(zl);
    const float pmax = dppMax(fmaxf(fmaxf(pm0, pm1), fmaxf(pm2, pm3)));
    const float target = P_MIN * Z;
    const float pTop = __uint_as_float(__float_as_uint(pmax) + 1u);

    // ---- sampled warm-start: 3 DUAL rounds (~6 probes) on p[0..3] ----
    float ssl = 0.0f, ssh = pTop;
    {
        float eGl = 16.0f * dppSum(p[0] + p[1] + p[2] + p[3]);  // Ghat(0)
        float eGh = 0.0f;
        for (int it = 0; it < 3; ++it) {
            const float sB = 0.5f * (ssl + ssh);
            if (!(sB > ssl && sB < ssh)) break;
            float sA = ssl + (ssh - ssl) *
                       ((eGl - target) / fmaxf(eGl - eGh, 1e-30f));
            if (!(sA > ssl && sA < ssh)) sA = sB;
            const float t0 = fminf(sA, sB), t1 = fmaxf(sA, sB);

            float a0 = 0.0f, a1 = 0.0f;
            #pragma unroll
            for (int q = 0; q < 4; ++q) {
                a0 += (p[q] >= t0) ? p[q] : 0.0f;
                a1 += (p[q] >= t1) ? p[q] : 0.0f;
            }
            dppSum2(a0, a1);
            const float M0 = 16.0f * a0, M1 = 16.0f * a1;   // M0 >= M1
            if      (M1 >= target) { ssl = t1; eGl = M1; }
            else if (M0 >= target) { ssl = t0; eGl = M0;
                                     ssh = t1; eGh = M1; }
            else                   { ssh = t0; eGh = M0; }
        }
    }

    // ---- Phase A0: dual-threshold pass, evaluates ssl AND ssh at once ----
    // Invariant from here: G(sl) >= target > G(sh), G(s) = mass of {p >= s}.
    float sl = 0.0f, sh = pTop;
    float Gl = Z,    Gh = 0.0f;
    int   Cl = MCOLS, Ch = 0;
    {
        float ml = 0.0f, mh = 0.0f;
        int   cl_ = 0,   ch_ = 0;
        #pragma unroll
        for (int k = 0; k < KPT; ++k) {
            const float pk = p[k];
            const bool gl = (pk >= ssl);
            const bool gh = (pk >= ssh);
            ml += gl ? pk : 0.0f; cl_ += (int)__popcll(__ballot(gl));
            mh += gh ? pk : 0.0f; ch_ += (int)__popcll(__ballot(gh));
        }
        dppSum2(ml, mh);
        if (ml >= target) { sl = ssl; Gl = ml; Cl = cl_; }
        else              { sh = ssl; Gh = ml; Ch = cl_; }
        if (mh >= target) { sl = ssh; Gl = mh; Cl = ch_; }
        else if (ssh < sh){ sh = ssh; Gh = mh; Ch = ch_; }
    }

    // ---- Phase A: exact probes until band <= 256 (4-chain scans) ----
    for (int it = 0; it < 10 && (Cl - Ch) > 256; ++it) {
        float s;
        if (it & 1) {
            s = 0.5f * (sl + sh);
        } else {
            const float den = fmaxf(Gl - Gh, 1e-30f);
            s = sl + (sh - sl) * ((Gl - target) / den);
        }
        if (!(s > sl && s < sh)) s = 0.5f * (sl + sh);
        if (!(s > sl && s < sh)) break;        // ulp-width bracket

        float m0 = 0.0f, m1 = 0.0f, m2 = 0.0f, m3 = 0.0f;
        int   c = 0;
        #pragma unroll
        for (int k = 0; k < KPT; k += 4) {
            const bool g0 = (p[k]     >= s);
            const bool g1 = (p[k + 1] >= s);
            const bool g2 = (p[k + 2] >= s);
            const bool g3 = (p[k + 3] >= s);
            m0 += g0 ? p[k]     : 0.0f; c += (int)__popcll(__ballot(g0));
            m1 += g1 ? p[k + 1] : 0.0f; c += (int)__popcll(__ballot(g1));
            m2 += g2 ? p[k + 2] : 0.0f; c += (int)__popcll(__ballot(g2));
            m3 += g3 ? p[k + 3] : 0.0f; c += (int)__popcll(__ballot(g3));
        }
        const float m = dppSum((m0 + m1) + (m2 + m3));
        if (m >= target) { sl = s; Gl = m; Cl = c; }
        else             { sh = s; Gh = m; Ch = c; }
    }

    // ---- Phase B: compact band [sl, sh) into 4 regs per lane ----
    int C = 0;
    #pragma unroll
    for (int k = 0; k < KPT; ++k) {
        const bool band = (p[k] >= sl) && (p[k] < sh);
        const unsigned long long mk = __ballot(band);
        if (band) {
            const unsigned mlo = (unsigned)mk, mhi = (unsigned)(mk >> 32);
            const int within = __builtin_amdgcn_mbcnt_hi(
                                   mhi, __builtin_amdgcn_mbcnt_lo(mlo, 0));
            const int pos = C + within;
            if (pos < 256) scomp[wid * 256 + pos] = p[k];
        }
        C += (int)__popcll(mk);
    }
    __builtin_amdgcn_s_waitcnt(0);             // drain ds_writes (same wave)
    float cp[4];
    bool  cv[4];
    #pragma unroll
    for (int q = 0; q < 4; ++q) {
        const int idx = q * 64 + lane;
        cv[q] = (idx < C) && (idx < 256);
        cp[q] = cv[q] ? scomp[wid * 256 + idx] : 0.0f;
    }

    float pstar, mb = 0.0f;
    int   cnt = 1;
    bool  haveTie;

    if (C > 256) {
        // fallback (rare): keep everything >= sl (off by <=2 boundary elems)
        pstar = (sl > 0.0f) ? __uint_as_float(__float_as_uint(sl) - 1u) : 0.0f;
        haveTie = false;
    } else {
        // ---- Phase C1: fine probes, 2 thresholds per round ----
        float lo_s = sl, hi_s = sh, lo_G = Gl, hi_G = Gh;
        int   lo_C = Cl, hi_C = Ch;
        for (int it = 0; it < 6 && (lo_C - hi_C) > 2; ++it) {
            const float sB = 0.5f * (lo_s + hi_s);
            if (!(sB > lo_s && sB < hi_s)) break;   // ulp-width bracket
            float sA = lo_s + (hi_s - lo_s) *
                       ((lo_G - target) / fmaxf(lo_G - hi_G, 1e-30f));
            if (!(sA > lo_s && sA < hi_s)) sA = sB;
            const float t0 = fminf(sA, sB), t1 = fmaxf(sA, sB);

            float a0 = 0.0f, a1 = 0.0f;
            int   k0 = 0,    k1 = 0;
            #pragma unroll
            for (int q = 0; q < 4; ++q) {
                const bool g0 = cv[q] && (cp[q] >= t0);
                const bool g1 = cv[q] && (cp[q] >= t1);
                a0 += g0 ? cp[q] : 0.0f; k0 += (int)__popcll(__ballot(g0));
                a1 += g1 ? cp[q] : 0.0f; k1 += (int)__popcll(__ballot(g1));
            }
            dppSum2(a0, a1);
            const float M0 = Gh + a0, M1 = Gh + a1;    // M0 >= M1
            const int   D0 = Ch + k0, D1 = Ch + k1;
            if      (M1 >= target) { lo_s = t1; lo_G = M1; lo_C = D1; }
            else if (M0 >= target) { lo_s = t0; lo_G = M0; lo_C = D0;
                                     hi_s = t1; hi_G = M1; hi_C = D1; }
            else                   { hi_s = t0; hi_G = M0; hi_C = D0; }
        }

        // ---- Phase C2: exact distinct-value walk downward from hi_s ----
        float scur = hi_s, M = hi_G;
        bool ok = false;
        pstar = lo_s;
        for (int e = 0; e < 16; ++e) {
            float vl = 0.0f;
            #pragma unroll
            for (int q = 0; q < 4; ++q)
                vl = fmaxf(vl, (cv[q] && cp[q] < scur) ? cp[q] : 0.0f);
            const float v = dppMax(vl);
            if (!(v > 0.0f)) break;            // fp knife-edge; fallback
            int cvn = 0;
            #pragma unroll
            for (int q = 0; q < 4; ++q)
                cvn += (int)__popcll(__ballot(cv[q] && (cp[q] == v)));
            const float Mn = M + v * (float)cvn;  // exact: ties bit-identical
            if (Mn >= target) { pstar = v; mb = M; cnt = cvn; ok = true; break; }
            M = Mn; scur = v;
        }
        haveTie = ok;
        if (!ok) {
            pstar = (lo_s > 0.0f) ? __uint_as_float(__float_as_uint(lo_s) - 1u)
                                  : 0.0f;
        }
    }

    // ---- Phase D: spd = sum_{p > p*} pd, 4-chain masked add (no logs) ----
    float s0 = 0.0f, s1 = 0.0f, s2 = 0.0f, s3 = 0.0f;
    #pragma unroll
    for (int k = 0; k < KPT; k += 4) {
        s0 += (p[k]     > pstar) ? pd[k]     : 0.0f;
        s1 += (p[k + 1] > pstar) ? pd[k + 1] : 0.0f;
        s2 += (p[k + 2] > pstar) ? pd[k + 2] : 0.0f;
        s3 += (p[k + 3] > pstar) ? pd[k + 3] : 0.0f;
    }
    const float spd = dppSum((s0 + s1) + (s2 + s3));

    if (lane == 0) {
        float tie = 0.0f;
        if (haveTie) {
            const float R = (target - mb) / pstar;      // exclusive-csum rule
            int q = (int)ceilf(R);
            if (q < 1) q = 1;
            if (q > cnt) q = cnt;
            tie = (float)q * pstar * (-__logf(pstar));
        }
        wacc[wid] = (spd + tie) / Z;
    }
    __syncthreads();                     // all waves reach exactly once
    if (tid == 0) {
        const float v = wacc[0] + wacc[1] + wacc[2] + wacc[3];
        if (partial) partial[blockIdx.x] = v;   // no same-address atomic
        else         atomicAdd(out, v);         // ws_size fallback
    }
}

// Deterministic 2nd-stage reduce: nblocks (<=4096) floats -> out[0].
__global__ __launch_bounds__(1024) void apml_reduce(
        const float* __restrict__ partial, float* __restrict__ out, int n) {
    __shared__ float s[16];
    const int t = threadIdx.x;
    float a = 0.0f;
    #pragma unroll
    for (int q = 0; q < 4; ++q) {
        const int i = t * 4 + q;
        a += (i < n) ? partial[i] : 0.0f;
    }
    a = dppSum(a);
    if ((t & 63) == 0) s[t >> 6] = a;
    __syncthreads();
    if (t == 0) {
        float r = 0.0f;
        #pragma unroll
        for (int w = 0; w < 16; ++w) r += s[w];
        out[0] = r;
    }
}

extern "C" void kernel_launch(void* const* d_in, const int* in_sizes, int n_in,
                              void* d_out, int out_size, void* d_ws, size_t ws_size,
                              hipStream_t stream) {
    const float* x = (const float*)d_in[0];   // [B, N, 3]
    const float* y = (const float*)d_in[1];   // [B, M, 3]
    float* out = (float*)d_out;               // scalar

    const int nrows = in_sizes[0] / 3;        // B * N
    const int nblocks = nrows / WPB;          // 4096

    if (d_ws && ws_size >= (size_t)nblocks * sizeof(float) && nblocks <= 4096) {
        float* partial = (float*)d_ws;
        apml_row_wave<<<nblocks, WPB * 64, 0, stream>>>(x, y, partial, out);
        apml_reduce<<<1, 1024, 0, stream>>>(partial, out, nblocks);
    } else {
        hipMemsetAsync(out, 0, sizeof(float), stream);   // capture-legal
        apml_row_wave<<<nblocks, WPB * 64, 0, stream>>>(x, y, nullptr, out);
    }
}